// Round 1
// 397.807 us; speedup vs baseline: 1.0095x; 1.0095x over previous
//
#include <hip/hip_runtime.h>

// Problem constants (fixed by the reference's setup_inputs).
constexpr int B  = 128;          // B_IMG * P * P = 32*2*2
constexpr int C  = 128;
constexpr int H  = 56, W = 56;
constexpr int HO = H + 2, WO = W + 2;        // 58 x 58
constexpr int PLANE_IN  = H * W;             // 3136
constexpr int PLANE_OUT = HO * WO;           // 3364 = 841 aligned float4
constexpr int NV4       = PLANE_OUT / 4;     // 841

__global__ __launch_bounds__(256) void pad2d_kernel(
    const float* __restrict__ x,
    const float* __restrict__ topW, const float* __restrict__ botW,
    const float* __restrict__ leftW, const float* __restrict__ rightW,
    const float* __restrict__ tlW,  const float* __restrict__ trW,
    const float* __restrict__ blW,  const float* __restrict__ brW,
    const int* __restrict__ np_ptr,
    float* __restrict__ out)
{
    const int plane = blockIdx.x;            // 0 .. B*C-1
    const int b   = plane / C;               // batch index
    const int c   = plane - b * C;           // channel
    const int tid = threadIdx.x;

    // Block-uniform zero masks (SGPR) -------------------------------------
    const int Pn = *np_ptr;                  // 2
    const int within = b % (Pn * Pn);
    const bool tz = within < Pn;
    const bool bz = within >= Pn * Pn - Pn;
    const bool lz = (b % Pn) == 0;
    const bool rz = (b % Pn) == Pn - 1;

    // Block-uniform channel weights (SGPR) --------------------------------
    const float tw = topW[c],  bw = botW[c];
    const float lw = leftW[c], rw = rightW[c];
    const float tl = tlW[c],   tr = trW[c];
    const float bl = blW[c],   br = brW[c];

    const float* __restrict__ xin = x + (size_t)plane * PLANE_IN;
    float4* __restrict__ o4 = (float4*)(out + (size_t)plane * PLANE_OUT);

    // Per-output-element value (r = out row 0..57, cc = out col 0..57).
    auto elem = [&](int r, int cc) -> float {
        if ((r >= 1) & (r <= H) & (cc >= 1) & (cc <= W))
            return xin[(r - 1) * W + (cc - 1)];            // interior copy
        if (r == 0) {                                       // top edge
            if (cc == 0)      return (tz | lz) ? 0.f : tl * xin[0];
            if (cc == WO - 1) return (tz | rz) ? 0.f : tr * xin[W - 1];
            return tz ? 0.f : tw * (xin[cc - 1] + xin[W + cc - 1]);
        }
        if (r == HO - 1) {                                  // bottom edge
            if (cc == 0)      return (bz | lz) ? 0.f : bl * xin[(H - 1) * W];
            if (cc == WO - 1) return (bz | rz) ? 0.f : br * xin[(H - 1) * W + W - 1];
            return bz ? 0.f : bw * (xin[(H - 2) * W + cc - 1] + xin[(H - 1) * W + cc - 1]);
        }
        if (cc == 0)                                        // left edge
            return lz ? 0.f : lw * (xin[(r - 1) * W] + xin[(r - 1) * W + 1]);
        // right edge
        return rz ? 0.f : rw * (xin[(r - 1) * W + W - 2] + xin[(r - 1) * W + W - 1]);
    };

    // Output-driven: one aligned float4 store per thread-iteration.
    // Every store instruction writes 64 lanes x 16 B contiguous = fully
    // dirty 64B granules; no partial-sector writes anywhere.
    for (int v = tid; v < NV4; v += 256) {
        const int j0 = v * 4;
        int r  = j0 / WO;                    // magic-mul division
        int cc = j0 - r * WO;
        float4 ov;
        ov.x = elem(r, cc);
        ++cc; if (cc == WO) { cc = 0; ++r; } // at most one row-wrap per float4
        ov.y = elem(r, cc);
        ++cc; if (cc == WO) { cc = 0; ++r; }
        ov.z = elem(r, cc);
        ++cc; if (cc == WO) { cc = 0; ++r; }
        ov.w = elem(r, cc);
        o4[v] = ov;
    }
}

extern "C" void kernel_launch(void* const* d_in, const int* in_sizes, int n_in,
                              void* d_out, int out_size, void* d_ws, size_t ws_size,
                              hipStream_t stream) {
    const float* x      = (const float*)d_in[0];
    const float* topW   = (const float*)d_in[1];
    const float* botW   = (const float*)d_in[2];
    const float* leftW  = (const float*)d_in[3];
    const float* rightW = (const float*)d_in[4];
    const float* tlW    = (const float*)d_in[5];
    const float* trW    = (const float*)d_in[6];
    const float* blW    = (const float*)d_in[7];
    const float* brW    = (const float*)d_in[8];
    // d_in[9] = padding (fixed 1), d_in[10] = num_patches
    const int* np_ptr   = (const int*)d_in[10];
    float* out = (float*)d_out;

    pad2d_kernel<<<dim3(B * C), dim3(256), 0, stream>>>(
        x, topW, botW, leftW, rightW, tlW, trW, blW, brW, np_ptr, out);
}

// Round 2
// 378.930 us; speedup vs baseline: 1.0598x; 1.0498x over previous
//
#include <hip/hip_runtime.h>

// Problem constants (fixed by the reference's setup_inputs).
constexpr int B  = 128;          // B_IMG * P * P = 32*2*2
constexpr int C  = 128;
constexpr int H  = 56, W = 56;
constexpr int HO = H + 2, WO = W + 2;        // 58 x 58
constexpr int PLANE_IN  = H * W;             // 3136 floats = 12.544 KB
constexpr int PLANE_OUT = HO * WO;           // 3364 = 841 aligned float4
constexpr int NV4_IN    = PLANE_IN / 4;      // 784
constexpr int NV4_OUT   = PLANE_OUT / 4;     // 841

__global__ __launch_bounds__(256) void pad2d_kernel(
    const float* __restrict__ x,
    const float* __restrict__ topW, const float* __restrict__ botW,
    const float* __restrict__ leftW, const float* __restrict__ rightW,
    const float* __restrict__ tlW,  const float* __restrict__ trW,
    const float* __restrict__ blW,  const float* __restrict__ brW,
    const int* __restrict__ np_ptr,
    float* __restrict__ out)
{
    __shared__ float sx[PLANE_IN];           // whole input plane in LDS

    const int plane = blockIdx.x;            // 0 .. B*C-1
    const int b   = plane / C;               // batch index
    const int c   = plane - b * C;           // channel
    const int tid = threadIdx.x;

    // ---- Phase 1: branch-free, batched global->LDS staging --------------
    // 784 aligned float4 loads; 3-4 per thread issued back-to-back, so the
    // wave has all its HBM latency in flight at once (one vmcnt wait).
    {
        const float4* __restrict__ x4 = (const float4*)(x + (size_t)plane * PLANE_IN);
        float4* __restrict__ s4 = (float4*)sx;
        for (int i = tid; i < NV4_IN; i += 256)
            s4[i] = x4[i];
    }

    // Block-uniform zero masks (SGPR) -------------------------------------
    const int Pn = *np_ptr;                  // 2
    const int within = b % (Pn * Pn);
    const bool tz = within < Pn;
    const bool bz = within >= Pn * Pn - Pn;
    const bool lz = (b % Pn) == 0;
    const bool rz = (b % Pn) == Pn - 1;

    // Block-uniform channel weights (SGPR) --------------------------------
    const float tw = topW[c],  bw = botW[c];
    const float lw = leftW[c], rw = rightW[c];
    const float tl = tlW[c],   tr = trW[c];
    const float bl = blW[c],   br = brW[c];

    __syncthreads();

    float4* __restrict__ o4 = (float4*)(out + (size_t)plane * PLANE_OUT);

    // Per-output-element value (r = out row 0..57, cc = out col 0..57).
    // All reads hit LDS: divergence here costs short lgkmcnt waits, not
    // serialized HBM latencies.
    auto elem = [&](int r, int cc) -> float {
        if ((r >= 1) & (r <= H) & (cc >= 1) & (cc <= W))
            return sx[(r - 1) * W + (cc - 1)];             // interior copy
        if (r == 0) {                                       // top edge
            if (cc == 0)      return (tz | lz) ? 0.f : tl * sx[0];
            if (cc == WO - 1) return (tz | rz) ? 0.f : tr * sx[W - 1];
            return tz ? 0.f : tw * (sx[cc - 1] + sx[W + cc - 1]);
        }
        if (r == HO - 1) {                                  // bottom edge
            if (cc == 0)      return (bz | lz) ? 0.f : bl * sx[(H - 1) * W];
            if (cc == WO - 1) return (bz | rz) ? 0.f : br * sx[(H - 1) * W + W - 1];
            return bz ? 0.f : bw * (sx[(H - 2) * W + cc - 1] + sx[(H - 1) * W + cc - 1]);
        }
        if (cc == 0)                                        // left edge
            return lz ? 0.f : lw * (sx[(r - 1) * W] + sx[(r - 1) * W + 1]);
        // right edge
        return rz ? 0.f : rw * (sx[(r - 1) * W + W - 2] + sx[(r - 1) * W + W - 1]);
    };

    // ---- Phase 2: output-driven aligned float4 stores -------------------
    // One dependency-free global store per iteration; global write stream
    // is fully dirty 64B granules.
    for (int v = tid; v < NV4_OUT; v += 256) {
        const int j0 = v * 4;
        int r  = j0 / WO;                    // magic-mul division
        int cc = j0 - r * WO;
        float4 ov;
        ov.x = elem(r, cc);
        ++cc; if (cc == WO) { cc = 0; ++r; } // at most one row-wrap per float4
        ov.y = elem(r, cc);
        ++cc; if (cc == WO) { cc = 0; ++r; }
        ov.z = elem(r, cc);
        ++cc; if (cc == WO) { cc = 0; ++r; }
        ov.w = elem(r, cc);
        o4[v] = ov;
    }
}

extern "C" void kernel_launch(void* const* d_in, const int* in_sizes, int n_in,
                              void* d_out, int out_size, void* d_ws, size_t ws_size,
                              hipStream_t stream) {
    const float* x      = (const float*)d_in[0];
    const float* topW   = (const float*)d_in[1];
    const float* botW   = (const float*)d_in[2];
    const float* leftW  = (const float*)d_in[3];
    const float* rightW = (const float*)d_in[4];
    const float* tlW    = (const float*)d_in[5];
    const float* trW    = (const float*)d_in[6];
    const float* blW    = (const float*)d_in[7];
    const float* brW    = (const float*)d_in[8];
    // d_in[9] = padding (fixed 1), d_in[10] = num_patches
    const int* np_ptr   = (const int*)d_in[10];
    float* out = (float*)d_out;

    pad2d_kernel<<<dim3(B * C), dim3(256), 0, stream>>>(
        x, topW, botW, leftW, rightW, tlW, trW, blW, brW, np_ptr, out);
}